// Round 1
// baseline (578.882 us; speedup 1.0000x reference)
//
#include <hip/hip_runtime.h>
#include <hip/hip_bf16.h>

// Problem constants: x(4,256,64,64), offset(4,18,64,64), mask(4,9,64,64),
// weight(256,256,3,3), out(4,256,64,64). stride=1, pad=1.
#define BN 4
#define CN 256
#define HN 64
#define WN 64
#define ON 256
#define KKN 9
#define HWN 4096      // 64*64
#define KDIM 2304     // 9*256

using frag_ab = __attribute__((ext_vector_type(8))) short;  // 8 bf16 in 4 VGPRs
using frag_cd = __attribute__((ext_vector_type(4))) float;  // 4 fp32 acc

static __device__ inline short f2bf(float f) {
    union { float f; unsigned u; } v; v.f = f;
    unsigned r = v.u + 0x7fffu + ((v.u >> 16) & 1u);  // round-to-nearest-even
    return (short)(r >> 16);
}

// ---------- kernel 1: x BCHW -> BHWC (fp32) ----------
__global__ __launch_bounds__(256) void transpose_x(const float* __restrict__ x,
                                                   float* __restrict__ xb) {
    __shared__ float tile[64][65];
    int bidx = blockIdx.x;            // 4 b * 4 ctiles * 64 ptiles = 1024
    int b   = bidx >> 8;
    int rem = bidx & 255;
    int c0  = (rem >> 6) * 64;
    int p0  = (rem & 63) * 64;
    int tid = threadIdx.x;
    int tp = tid & 63, tc = tid >> 6;
    for (int i = 0; i < 16; ++i) {
        int c = tc + i * 4;
        tile[c][tp] = x[(b * CN + c0 + c) * HWN + p0 + tp];
    }
    __syncthreads();
    int tcc = tid & 63, tpp = tid >> 6;
    for (int i = 0; i < 16; ++i) {
        int p = tpp + i * 4;
        xb[(b * HWN + p0 + p) * CN + c0 + tcc] = tile[tcc][p];
    }
}

// ---------- kernel 2: weight (O,C,3,3) fp32 -> bf16 [O][kk*256+c] ----------
__global__ __launch_bounds__(256) void repack_w(const float* __restrict__ wsrc,
                                                short* __restrict__ wt) {
    int t = blockIdx.x * 256 + threadIdx.x;   // < 589824
    int c = t & 255;
    int rest = t >> 8;                        // o*9 + kk
    int kk = rest % 9;
    int o  = rest / 9;
    float v = wsrc[(o * CN + c) * 9 + kk];
    wt[o * KDIM + kk * CN + c] = f2bf(v);
}

// ---------- main fused kernel ----------
struct __align__(16) SMem {
    union {
        struct {
            short A[64][72];     // Mtile x BK bf16, padded row (144B = 9*16)
            short Bm[256][72];   // N x BK bf16 (stored [n][k]), padded
            int   crow[64][4];   // per-m corner row offsets into xb
            float cwgt[64][4];   // per-m corner weights (mask folded, 0 if OOB)
        } s;
        float outb[64][261];     // epilogue transpose buffer [m][o], pad 261
    };
};

__global__ __launch_bounds__(256) void deform_main(const float* __restrict__ xb,
                                                   const short* __restrict__ wt,
                                                   const float* __restrict__ offs,
                                                   const float* __restrict__ maskp,
                                                   float* __restrict__ out) {
    __shared__ SMem sm;
    int tid  = threadIdx.x;
    int m0   = blockIdx.x * 64;      // 64 consecutive m => fixed (b,h), w=0..63
    int b    = m0 >> 12;
    int h    = (m0 >> 6) & 63;
    int wv   = tid >> 6;             // wave id 0..3 -> N cols [wv*64, wv*64+64)
    int lane = tid & 63;

    frag_cd acc[4][4];
    for (int i = 0; i < 4; ++i)
        for (int j = 0; j < 4; ++j)
            acc[i][j] = (frag_cd){0.f, 0.f, 0.f, 0.f};

    for (int kk = 0; kk < KKN; ++kk) {
        __syncthreads();
        if (tid < 64) {
            int w = tid;
            int ki = kk / 3, kj = kk % 3;
            int obase = ((b * 18 + kk * 2) * 64 + h) * 64 + w;
            float dy = offs[obase];
            float dx = offs[obase + HWN];
            float mv = maskp[((b * 9 + kk) * 64 + h) * 64 + w];
            float py = (float)(h - 1 + ki) + dy;
            float px = (float)(w - 1 + kj) + dx;
            float y0f = floorf(py), x0f = floorf(px);
            float wy = py - y0f, wx = px - x0f;
            int y0 = (int)y0f, x0 = (int)x0f;
            #pragma unroll
            for (int cy = 0; cy < 2; ++cy)
                #pragma unroll
                for (int cx = 0; cx < 2; ++cx) {
                    int yy = y0 + cy, xx = x0 + cx;
                    float wgt = (cy ? wy : 1.f - wy) * (cx ? wx : 1.f - wx) * mv;
                    bool valid = (yy >= 0 && yy < HN && xx >= 0 && xx < WN);
                    int yc = min(max(yy, 0), HN - 1);
                    int xc = min(max(xx, 0), WN - 1);
                    sm.s.crow[w][cy * 2 + cx] = ((b * HN + yc) * WN + xc) * CN;
                    sm.s.cwgt[w][cy * 2 + cx] = valid ? wgt : 0.f;
                }
        }
        __syncthreads();

        for (int c0 = 0; c0 < CN; c0 += 64) {
            // --- A fill: wave wv samples m = wv + 4*i, lane = c ---
            {
                int c = lane;
                #pragma unroll
                for (int i = 0; i < 16; ++i) {
                    int m = wv + 4 * i;
                    const int*   cr = sm.s.crow[m];
                    const float* cw = sm.s.cwgt[m];
                    float v = cw[0] * xb[cr[0] + c0 + c]
                            + cw[1] * xb[cr[1] + c0 + c]
                            + cw[2] * xb[cr[2] + c0 + c]
                            + cw[3] * xb[cr[3] + c0 + c];
                    sm.s.A[m][c] = f2bf(v);
                }
            }
            // --- B fill: [n][k] layout, 16B vector copies ---
            {
                int seg = tid & 7;
                int ob  = tid >> 3;
                #pragma unroll
                for (int it = 0; it < 8; ++it) {
                    int o = ob + 32 * it;
                    const frag_ab* src =
                        (const frag_ab*)(wt + o * KDIM + kk * CN + c0 + seg * 8);
                    *(frag_ab*)&sm.s.Bm[o][seg * 8] = *src;
                }
            }
            __syncthreads();
            // --- MFMA: 2 K-steps of 32 ---
            #pragma unroll
            for (int s = 0; s < 2; ++s) {
                int q = lane >> 4;
                int r = lane & 15;
                frag_ab af[4], bfm[4];
                #pragma unroll
                for (int i = 0; i < 4; ++i)
                    af[i] = *(const frag_ab*)&sm.s.A[i * 16 + r][s * 32 + q * 8];
                #pragma unroll
                for (int j = 0; j < 4; ++j)
                    bfm[j] = *(const frag_ab*)&sm.s.Bm[wv * 64 + j * 16 + r][s * 32 + q * 8];
                #pragma unroll
                for (int i = 0; i < 4; ++i)
                    #pragma unroll
                    for (int j = 0; j < 4; ++j)
                        acc[i][j] = __builtin_amdgcn_mfma_f32_16x16x32_bf16(
                            af[i], bfm[j], acc[i][j], 0, 0, 0);
            }
            __syncthreads();
        }
    }

    // ---- epilogue: transpose via LDS for coalesced BOHW stores ----
    {
        int q = lane >> 4, r = lane & 15;
        #pragma unroll
        for (int i = 0; i < 4; ++i)
            #pragma unroll
            for (int j = 0; j < 4; ++j) {
                int ml = i * 16 + q * 4;
                int ol = wv * 64 + j * 16 + r;
                sm.outb[ml + 0][ol] = acc[i][j][0];
                sm.outb[ml + 1][ol] = acc[i][j][1];
                sm.outb[ml + 2][ol] = acc[i][j][2];
                sm.outb[ml + 3][ol] = acc[i][j][3];
            }
    }
    __syncthreads();
    {
        int w = lane;
        for (int oo = 0; oo < 64; ++oo) {
            int o = oo * 4 + wv;
            out[((b * ON + o) * HN + h) * WN + w] = sm.outb[w][o];
        }
    }
}

extern "C" void kernel_launch(void* const* d_in, const int* in_sizes, int n_in,
                              void* d_out, int out_size, void* d_ws, size_t ws_size,
                              hipStream_t stream) {
    const float* x      = (const float*)d_in[0];
    const float* offset = (const float*)d_in[1];
    const float* mask   = (const float*)d_in[2];
    const float* weight = (const float*)d_in[3];
    float* out = (float*)d_out;

    // ws layout: xb (BHWC fp32, 16777216 B) | wt (bf16, 1179648 B)  => ~18 MB
    float* xb = (float*)d_ws;
    short* wt = (short*)((char*)d_ws + 16777216);

    hipLaunchKernelGGL(transpose_x, dim3(1024), dim3(256), 0, stream, x, xb);
    hipLaunchKernelGGL(repack_w,    dim3(2304), dim3(256), 0, stream, weight, wt);
    hipLaunchKernelGGL(deform_main, dim3(256),  dim3(256), 0, stream,
                       xb, wt, offset, mask, out);
}

// Round 2
// 195.108 us; speedup vs baseline: 2.9670x; 2.9670x over previous
//
#include <hip/hip_runtime.h>
#include <hip/hip_bf16.h>

// Problem: x(4,256,64,64), offset(4,18,64,64), mask(4,9,64,64),
// weight(256,256,3,3) -> out(4,256,64,64). stride=1, pad=1, K=3.
// Decomposition: BCHW->BHWC transpose | weight repack bf16 | bilinear sample
// to A[16384][2304] bf16 | MFMA GEMM (M=16384,N=256,K=2304) + BOHW epilogue.
#define BN 4
#define CN 256
#define HN 64
#define WN 64
#define ON 256
#define KKN 9
#define HWN 4096
#define KDIM 2304   // 9*256
#define MN 16384    // B*H*W

using frag_ab = __attribute__((ext_vector_type(8))) short;  // 8 bf16
using frag_cd = __attribute__((ext_vector_type(4))) float;  // 4 fp32

static __device__ inline short f2bf(float f) {
    union { float f; unsigned u; } v; v.f = f;
    unsigned r = v.u + 0x7fffu + ((v.u >> 16) & 1u);
    return (short)(r >> 16);
}

static __device__ inline void async_copy16(const void* g, void* l) {
    __builtin_amdgcn_global_load_lds(
        (const __attribute__((address_space(1))) unsigned int*)g,
        (__attribute__((address_space(3))) unsigned int*)l,
        16, 0, 0);
}

// ---------- kernel 1: x BCHW -> BHWC fp32 ----------
__global__ __launch_bounds__(256) void transpose_x(const float* __restrict__ x,
                                                   float* __restrict__ xb) {
    __shared__ float tile[64][65];
    int bidx = blockIdx.x;            // 4 b * 4 ctiles * 64 ptiles
    int b   = bidx >> 8;
    int rem = bidx & 255;
    int c0  = (rem >> 6) * 64;
    int p0  = (rem & 63) * 64;
    int tid = threadIdx.x;
    int tp = tid & 63, tc = tid >> 6;
    for (int i = 0; i < 16; ++i) {
        int c = tc + i * 4;
        tile[c][tp] = x[(b * CN + c0 + c) * HWN + p0 + tp];
    }
    __syncthreads();
    int tcc = tid & 63, tpp = tid >> 6;
    for (int i = 0; i < 16; ++i) {
        int p = tpp + i * 4;
        xb[(b * HWN + p0 + p) * CN + c0 + tcc] = tile[tcc][p];
    }
}

// ---------- kernel 2: weight (O,C,3,3) fp32 -> bf16 [O][kk*256+c] ----------
__global__ __launch_bounds__(256) void repack_w(const float* __restrict__ wsrc,
                                                short* __restrict__ wt) {
    int t = blockIdx.x * 256 + threadIdx.x;   // < 589824
    int c = t & 255;
    int rest = t >> 8;                        // o*9 + kk
    int kk = rest % 9;
    int o  = rest / 9;
    float v = wsrc[(o * CN + c) * 9 + kk];
    wt[o * KDIM + kk * CN + c] = f2bf(v);
}

// ---------- kernel 3: bilinear sample + modulate -> A[m][kk*256+c] bf16 ----
// grid = MN/2 blocks x 256 threads; thread handles one m (t>>7) and a c-pair.
__global__ __launch_bounds__(256) void sample_kernel(const float* __restrict__ xb,
                                                     const float* __restrict__ offs,
                                                     const float* __restrict__ maskp,
                                                     short* __restrict__ A) {
    int t  = threadIdx.x;
    int m  = blockIdx.x * 2 + (t >> 7);
    int b  = m >> 12;
    int h  = (m >> 6) & 63;
    int w  = m & 63;
    int cp = (t & 127) * 2;
    #pragma unroll
    for (int kk = 0; kk < KKN; ++kk) {
        int ki = kk / 3, kj = kk - ki * 3;
        int obase = ((b * 18 + kk * 2) * 64 + h) * 64 + w;
        float dy = offs[obase];
        float dx = offs[obase + HWN];
        float mv = maskp[((b * 9 + kk) * 64 + h) * 64 + w];
        float py = (float)(h - 1 + ki) + dy;
        float px = (float)(w - 1 + kj) + dx;
        float y0f = floorf(py), x0f = floorf(px);
        float wy = py - y0f, wx = px - x0f;
        int y0 = (int)y0f, x0 = (int)x0f;
        float v0 = 0.f, v1 = 0.f;
        #pragma unroll
        for (int cy = 0; cy < 2; ++cy)
            #pragma unroll
            for (int cx = 0; cx < 2; ++cx) {
                int yy = y0 + cy, xx = x0 + cx;
                // wave-uniform branch: all 64 lanes share (m,kk)
                if (yy >= 0 && yy < HN && xx >= 0 && xx < WN) {
                    float wgt = (cy ? wy : 1.f - wy) * (cx ? wx : 1.f - wx) * mv;
                    const float2 vv =
                        *(const float2*)&xb[(((b * HN + yy) * WN + xx) << 8) + cp];
                    v0 += wgt * vv.x;
                    v1 += wgt * vv.y;
                }
            }
        short2 st;
        st.x = f2bf(v0);
        st.y = f2bf(v1);
        *(short2*)&A[(size_t)m * KDIM + kk * CN + cp] = st;
    }
}

// ---------- kernel 4: GEMM  C[m][o] = A[m][k] . wt[o][k], epilogue -> BOHW --
// MT=128, NT=64, BK=64. grid = (16384/128)*(256/64) = 512 blocks.
#define MT 128
#define NT 64
#define BK 64

__global__ __launch_bounds__(256) void gemm_kernel(const short* __restrict__ A,
                                                   const short* __restrict__ wt,
                                                   float* __restrict__ out) {
    __shared__ union {
        struct { short A[MT * BK]; short B[NT * BK]; } st;  // 16 KB + 8 KB
        float outb[MT][65];                                  // 33.3 KB
    } sm;
    int tid  = threadIdx.x;
    int bid  = blockIdx.x;
    int mblk = bid >> 2, oblk = bid & 3;
    int m0 = mblk * MT, o0 = oblk * NT;
    int wv = tid >> 6, lane = tid & 63;
    int q = lane >> 4, r = lane & 15;

    frag_cd acc[2][4];
    #pragma unroll
    for (int i = 0; i < 2; ++i)
        #pragma unroll
        for (int j = 0; j < 4; ++j)
            acc[i][j] = (frag_cd){0.f, 0.f, 0.f, 0.f};

    int arow = tid >> 3, aseg = tid & 7;   // staging: row-within-32, 16B seg

    for (int k0 = 0; k0 < KDIM; k0 += BK) {
        __syncthreads();
        // A tile: 128 rows x 64 k, XOR-swizzled segs (conflict-free unpadded)
        #pragma unroll
        for (int it = 0; it < 4; ++it) {
            int row = it * 32 + arow;
            const short* src = A + (size_t)(m0 + row) * KDIM + k0
                                 + ((aseg ^ (row & 7)) << 3);
            async_copy16(src, (char*)sm.st.A + (it * 256 + tid) * 16);
        }
        // B tile: 64 rows x 64 k
        #pragma unroll
        for (int it = 0; it < 2; ++it) {
            int row = it * 32 + arow;
            const short* src = wt + (size_t)(o0 + row) * KDIM + k0
                                  + ((aseg ^ (row & 7)) << 3);
            async_copy16(src, (char*)sm.st.B + (it * 256 + tid) * 16);
        }
        __syncthreads();
        #pragma unroll
        for (int s = 0; s < 2; ++s) {
            frag_ab af[2], bf[4];
            #pragma unroll
            for (int i = 0; i < 2; ++i) {
                int row = wv * 32 + i * 16 + r;
                af[i] = *(const frag_ab*)
                    &sm.st.A[row * BK + ((((s << 2) + q) ^ (row & 7)) << 3)];
            }
            #pragma unroll
            for (int j = 0; j < 4; ++j) {
                int row = j * 16 + r;
                bf[j] = *(const frag_ab*)
                    &sm.st.B[row * BK + ((((s << 2) + q) ^ (row & 7)) << 3)];
            }
            #pragma unroll
            for (int i = 0; i < 2; ++i)
                #pragma unroll
                for (int j = 0; j < 4; ++j)
                    acc[i][j] = __builtin_amdgcn_mfma_f32_16x16x32_bf16(
                        af[i], bf[j], acc[i][j], 0, 0, 0);
        }
    }
    __syncthreads();
    // epilogue: C-frag (row = q*4+reg, col = r) -> LDS -> coalesced BOHW
    #pragma unroll
    for (int i = 0; i < 2; ++i)
        #pragma unroll
        for (int j = 0; j < 4; ++j) {
            int ml = wv * 32 + i * 16 + q * 4;
            int ol = j * 16 + r;
            sm.outb[ml + 0][ol] = acc[i][j][0];
            sm.outb[ml + 1][ol] = acc[i][j][1];
            sm.outb[ml + 2][ol] = acc[i][j][2];
            sm.outb[ml + 3][ol] = acc[i][j][3];
        }
    __syncthreads();
    int b = m0 >> 12, h0 = (m0 >> 6) & 63;
    int w = tid & 63, sub = tid >> 6;
    #pragma unroll
    for (int oo = 0; oo < 16; ++oo) {
        int ol = oo * 4 + sub;
        #pragma unroll
        for (int hh = 0; hh < 2; ++hh) {
            out[(((size_t)b * ON + o0 + ol) * HN + h0 + hh) * WN + w] =
                sm.outb[hh * 64 + w][ol];
        }
    }
}

extern "C" void kernel_launch(void* const* d_in, const int* in_sizes, int n_in,
                              void* d_out, int out_size, void* d_ws, size_t ws_size,
                              hipStream_t stream) {
    const float* x      = (const float*)d_in[0];
    const float* offset = (const float*)d_in[1];
    const float* mask   = (const float*)d_in[2];
    const float* weight = (const float*)d_in[3];
    float* out = (float*)d_out;

    // ws: xb fp32 16 MiB | wt bf16 1.125 MiB | A bf16 72 MiB  (~93.5 MB)
    float* xb = (float*)d_ws;
    short* wt = (short*)((char*)d_ws + 16777216);
    short* A  = (short*)((char*)d_ws + 16777216 + 1179648);

    hipLaunchKernelGGL(transpose_x,   dim3(1024),   dim3(256), 0, stream, x, xb);
    hipLaunchKernelGGL(repack_w,      dim3(2304),   dim3(256), 0, stream, weight, wt);
    hipLaunchKernelGGL(sample_kernel, dim3(MN / 2), dim3(256), 0, stream,
                       xb, offset, mask, A);
    hipLaunchKernelGGL(gemm_kernel,   dim3(512),    dim3(256), 0, stream,
                       A, wt, out);
}

// Round 3
// 187.214 us; speedup vs baseline: 3.0921x; 1.0422x over previous
//
#include <hip/hip_runtime.h>
#include <hip/hip_bf16.h>

// Problem: x(4,256,64,64), offset(4,18,64,64), mask(4,9,64,64),
// weight(256,256,3,3) -> out(4,256,64,64). stride=1, pad=1, K=3.
// Pipeline: prep (BCHW->BHWC fp32 | weight->bf16 [O][kk*256+c] | zero out)
//   -> sample (bilinear+modulate -> A[16384][2304] bf16)
//   -> GEMM (M=16384,N=256,K=2304 bf16 MFMA, K-split=2, atomic f32 epilogue).
#define BN 4
#define CN 256
#define HN 64
#define WN 64
#define ON 256
#define KKN 9
#define HWN 4096
#define KDIM 2304   // 9*256
#define MN 16384    // B*H*W
#define KS 2        // K-split
#define KHALF 1152

using frag_ab = __attribute__((ext_vector_type(8))) short;  // 8 bf16
using frag_cd = __attribute__((ext_vector_type(4))) float;  // 4 fp32

static __device__ inline short f2bf(float f) {
    union { float f; unsigned u; } v; v.f = f;
    unsigned r = v.u + 0x7fffu + ((v.u >> 16) & 1u);
    return (short)(r >> 16);
}

static __device__ inline void async_copy16(const void* g, void* l) {
    __builtin_amdgcn_global_load_lds(
        (const __attribute__((address_space(1))) unsigned int*)g,
        (__attribute__((address_space(3))) unsigned int*)l,
        16, 0, 0);
}

// ---------- kernel 1: prep = transpose_x | repack_w | zero_out ----------
// blocks [0,1024): x BCHW->BHWC tile transpose
// blocks [1024,3328): weight fp32 (O,C,3,3) -> bf16 [O][kk*256+c]
// blocks [3328,4352): zero d_out (4.19M floats, 16 per thread)
__global__ __launch_bounds__(256) void prep_kernel(const float* __restrict__ x,
                                                   const float* __restrict__ wsrc,
                                                   float* __restrict__ xb,
                                                   short* __restrict__ wt,
                                                   float* __restrict__ outz) {
    int bidx = blockIdx.x;
    int tid  = threadIdx.x;
    if (bidx < 1024) {
        __shared__ float tile[64][65];
        int b   = bidx >> 8;
        int rem = bidx & 255;
        int c0  = (rem >> 6) * 64;
        int p0  = (rem & 63) * 64;
        int tp = tid & 63, tc = tid >> 6;
        for (int i = 0; i < 16; ++i) {
            int c = tc + i * 4;
            tile[c][tp] = x[(b * CN + c0 + c) * HWN + p0 + tp];
        }
        __syncthreads();
        int tcc = tid & 63, tpp = tid >> 6;
        for (int i = 0; i < 16; ++i) {
            int p = tpp + i * 4;
            xb[(b * HWN + p0 + p) * CN + c0 + tcc] = tile[tcc][p];
        }
    } else if (bidx < 3328) {
        int t = (bidx - 1024) * 256 + tid;    // < 589824
        int c = t & 255;
        int rest = t >> 8;                    // o*9 + kk
        int kk = rest % 9;
        int o  = rest / 9;
        float v = wsrc[(o * CN + c) * 9 + kk];
        wt[o * KDIM + kk * CN + c] = f2bf(v);
    } else {
        int t = (bidx - 3328) * 256 + tid;    // < 262144, 16 floats each
        float4 z = {0.f, 0.f, 0.f, 0.f};
        float4* p = (float4*)outz + (size_t)t * 4;
        p[0] = z; p[1] = z; p[2] = z; p[3] = z;
    }
}

// ---------- kernel 2: bilinear sample + modulate -> A[m][kk*256+c] bf16 ----
// grid = MN/4 blocks x 256 threads; wave handles one m, lane = c-quad.
__global__ __launch_bounds__(256) void sample_kernel(const float* __restrict__ xb,
                                                     const float* __restrict__ offs,
                                                     const float* __restrict__ maskp,
                                                     short* __restrict__ A) {
    int t  = threadIdx.x;
    int m  = blockIdx.x * 4 + (t >> 6);
    int b  = m >> 12;
    int h  = (m >> 6) & 63;
    int w  = m & 63;
    int c0 = (t & 63) * 4;
    #pragma unroll
    for (int kk = 0; kk < KKN; ++kk) {
        int ki = kk / 3, kj = kk - ki * 3;
        int obase = ((b * 18 + kk * 2) * 64 + h) * 64 + w;
        float dy = offs[obase];
        float dx = offs[obase + HWN];
        float mv = maskp[((b * 9 + kk) * 64 + h) * 64 + w];
        float py = (float)(h - 1 + ki) + dy;
        float px = (float)(w - 1 + kj) + dx;
        float y0f = floorf(py), x0f = floorf(px);
        float wy = py - y0f, wx = px - x0f;
        int y0 = (int)y0f, x0 = (int)x0f;
        float4 acc = {0.f, 0.f, 0.f, 0.f};
        #pragma unroll
        for (int cy = 0; cy < 2; ++cy)
            #pragma unroll
            for (int cx = 0; cx < 2; ++cx) {
                int yy = y0 + cy, xx = x0 + cx;
                // wave-uniform branch: all 64 lanes share (m,kk)
                if (yy >= 0 && yy < HN && xx >= 0 && xx < WN) {
                    float wgt = (cy ? wy : 1.f - wy) * (cx ? wx : 1.f - wx) * mv;
                    const float4 vv =
                        *(const float4*)&xb[(((b * HN + yy) * WN + xx) << 8) + c0];
                    acc.x += wgt * vv.x;
                    acc.y += wgt * vv.y;
                    acc.z += wgt * vv.z;
                    acc.w += wgt * vv.w;
                }
            }
        short4 st;
        st.x = f2bf(acc.x);
        st.y = f2bf(acc.y);
        st.z = f2bf(acc.z);
        st.w = f2bf(acc.w);
        *(short4*)&A[(size_t)m * KDIM + kk * CN + c0] = st;
    }
}

// ---------- kernel 3: GEMM with K-split, atomic f32 epilogue ----------
// MT=128, NT=64, BK=64, KS=2. grid = 128 mblk * 4 oblk * 2 ks = 1024 blocks.
// bid mapping: mblk = bid&127, g = bid>>7 -> all 8 blocks sharing an A-tile
// land on the same XCD (bid mod 8 == mblk mod 8).
#define MT 128
#define NT 64
#define BK 64

__global__ __launch_bounds__(256, 4) void gemm_kernel(const short* __restrict__ A,
                                                      const short* __restrict__ wt,
                                                      float* __restrict__ out) {
    __shared__ union {
        struct { short A[MT * BK]; short B[NT * BK]; } st;  // 24 KB
        float outb[MT][65];                                  // 33.3 KB
    } sm;
    int tid  = threadIdx.x;
    int bid  = blockIdx.x;
    int mblk = bid & 127;
    int g    = bid >> 7;
    int oblk = g >> 1;
    int ks   = g & 1;
    int m0 = mblk * MT, o0 = oblk * NT;
    int kbeg = ks * KHALF;
    int wv = tid >> 6, lane = tid & 63;
    int q = lane >> 4, r = lane & 15;

    frag_cd acc[2][4];
    #pragma unroll
    for (int i = 0; i < 2; ++i)
        #pragma unroll
        for (int j = 0; j < 4; ++j)
            acc[i][j] = (frag_cd){0.f, 0.f, 0.f, 0.f};

    int arow = tid >> 3, aseg = tid & 7;

    for (int k0 = kbeg; k0 < kbeg + KHALF; k0 += BK) {
        __syncthreads();
        // A tile: 128 x 64, XOR-swizzled 16B segs
        #pragma unroll
        for (int it = 0; it < 4; ++it) {
            int row = it * 32 + arow;
            const short* src = A + (size_t)(m0 + row) * KDIM + k0
                                 + ((aseg ^ (row & 7)) << 3);
            async_copy16(src, (char*)sm.st.A + (it * 256 + tid) * 16);
        }
        // B tile: 64 x 64
        #pragma unroll
        for (int it = 0; it < 2; ++it) {
            int row = it * 32 + arow;
            const short* src = wt + (size_t)(o0 + row) * KDIM + k0
                                  + ((aseg ^ (row & 7)) << 3);
            async_copy16(src, (char*)sm.st.B + (it * 256 + tid) * 16);
        }
        __syncthreads();
        #pragma unroll
        for (int s = 0; s < 2; ++s) {
            frag_ab af[2], bf[4];
            #pragma unroll
            for (int i = 0; i < 2; ++i) {
                int row = wv * 32 + i * 16 + r;
                af[i] = *(const frag_ab*)
                    &sm.st.A[row * BK + ((((s << 2) + q) ^ (row & 7)) << 3)];
            }
            #pragma unroll
            for (int j = 0; j < 4; ++j) {
                int row = j * 16 + r;
                bf[j] = *(const frag_ab*)
                    &sm.st.B[row * BK + ((((s << 2) + q) ^ (row & 7)) << 3)];
            }
            #pragma unroll
            for (int i = 0; i < 2; ++i)
                #pragma unroll
                for (int j = 0; j < 4; ++j)
                    acc[i][j] = __builtin_amdgcn_mfma_f32_16x16x32_bf16(
                        af[i], bf[j], acc[i][j], 0, 0, 0);
        }
    }
    __syncthreads();
    // epilogue: C-frag (row = q*4+reg, col = r) -> LDS -> atomic BOHW adds
    #pragma unroll
    for (int i = 0; i < 2; ++i)
        #pragma unroll
        for (int j = 0; j < 4; ++j) {
            int ml = wv * 32 + i * 16 + q * 4;
            int ol = j * 16 + r;
            sm.outb[ml + 0][ol] = acc[i][j][0];
            sm.outb[ml + 1][ol] = acc[i][j][1];
            sm.outb[ml + 2][ol] = acc[i][j][2];
            sm.outb[ml + 3][ol] = acc[i][j][3];
        }
    __syncthreads();
    int b = m0 >> 12, h0 = (m0 >> 6) & 63;
    int w = tid & 63, sub = tid >> 6;
    #pragma unroll
    for (int oo = 0; oo < 16; ++oo) {
        int ol = oo * 4 + sub;
        #pragma unroll
        for (int hh = 0; hh < 2; ++hh) {
            unsafeAtomicAdd(
                &out[(((size_t)b * ON + o0 + ol) * HN + h0 + hh) * WN + w],
                sm.outb[hh * 64 + w][ol]);
        }
    }
}

extern "C" void kernel_launch(void* const* d_in, const int* in_sizes, int n_in,
                              void* d_out, int out_size, void* d_ws, size_t ws_size,
                              hipStream_t stream) {
    const float* x      = (const float*)d_in[0];
    const float* offset = (const float*)d_in[1];
    const float* mask   = (const float*)d_in[2];
    const float* weight = (const float*)d_in[3];
    float* out = (float*)d_out;

    // ws: xb fp32 16 MiB | wt bf16 1.125 MiB | A bf16 72 MiB  (~93.5 MB)
    float* xb = (float*)d_ws;
    short* wt = (short*)((char*)d_ws + 16777216);
    short* A  = (short*)((char*)d_ws + 16777216 + 1179648);

    hipLaunchKernelGGL(prep_kernel,   dim3(4352),   dim3(256), 0, stream,
                       x, weight, xb, wt, out);
    hipLaunchKernelGGL(sample_kernel, dim3(MN / 4), dim3(256), 0, stream,
                       xb, offset, mask, A);
    hipLaunchKernelGGL(gemm_kernel,   dim3(1024),   dim3(256), 0, stream,
                       A, wt, out);
}